// Round 6
// baseline (480.168 us; speedup 1.0000x reference)
//
#include <hip/hip_runtime.h>

#define BS 4
#define NS 16384
#define S_SAMP 8
#define CPL 64
#define RES 128
#define IN_DIM 192
#define NPTS (BS * NS)                 // 65536
#define PL_STRIDE (RES * RES * CPL)    // 1048576 floats per (batch,plane)
#define PLANES_T_FLOATS (BS * 3 * PL_STRIDE)

// ---------------------------------------------------------------------------
// Kernel 1: transpose planes [B,C,H,W] -> [B,pl,H,W,C]. float4 on both global
// sides (1KB/wave-instr); LDS pad 65 -> 2-way banks (free).
// ---------------------------------------------------------------------------
__global__ __launch_bounds__(256) void transpose_planes(
    const float* __restrict__ xz, const float* __restrict__ xy,
    const float* __restrict__ yz, float* __restrict__ T) {
  __shared__ float tile[64][65];
  int blk = blockIdx.x;
  int xh = blk & 1;                // 64-wide x half
  int y  = (blk >> 1) & 127;
  int pl = (blk >> 8) % 3;
  int b  = blk / 768;
  const float* s = ((pl == 0) ? xz : (pl == 1) ? xy : yz) +
                   (size_t)b * CPL * RES * RES + y * RES + xh * 64;
  int tid = threadIdx.x;
  int xi = tid & 15, c0 = tid >> 4;
#pragma unroll
  for (int r = 0; r < 4; ++r) {
    int c = c0 + r * 16;
    float4 v = *(const float4*)(s + (size_t)c * RES * RES + 4 * xi);
    tile[c][4 * xi + 0] = v.x;
    tile[c][4 * xi + 1] = v.y;
    tile[c][4 * xi + 2] = v.z;
    tile[c][4 * xi + 3] = v.w;
  }
  __syncthreads();
  float* d = T + ((size_t)(b * 3 + pl) * RES * RES + (size_t)y * RES + xh * 64) * CPL;
  int cj = tid & 15, x0 = tid >> 4;
#pragma unroll
  for (int r = 0; r < 4; ++r) {
    int x = x0 + r * 16;
    float4 v;
    v.x = tile[4 * cj + 0][x];
    v.y = tile[4 * cj + 1][x];
    v.z = tile[4 * cj + 2][x];
    v.w = tile[4 * cj + 3][x];
    *(float4*)(d + (size_t)x * CPL + 4 * cj) = v;
  }
}

// ---------------------------------------------------------------------------
// Kernel 2: Wc = W_out @ W_v (WcT[k][j]), bc = W_out @ b_v. 4-way ILP.
// ---------------------------------------------------------------------------
__global__ __launch_bounds__(192) void precompute_wc(
    const float* __restrict__ W_v, const float* __restrict__ b_v,
    const float* __restrict__ W_out, float* __restrict__ WcT,
    float* __restrict__ bc) {
  int j = blockIdx.x;
  int k = threadIdx.x;
  if (j < IN_DIM) {
    float a0 = 0.f, a1 = 0.f, a2 = 0.f, a3 = 0.f;
#pragma unroll 4
    for (int m = 0; m < IN_DIM; m += 4) {
      a0 += W_out[j * IN_DIM + m + 0] * W_v[(m + 0) * IN_DIM + k];
      a1 += W_out[j * IN_DIM + m + 1] * W_v[(m + 1) * IN_DIM + k];
      a2 += W_out[j * IN_DIM + m + 2] * W_v[(m + 2) * IN_DIM + k];
      a3 += W_out[j * IN_DIM + m + 3] * W_v[(m + 3) * IN_DIM + k];
    }
    WcT[k * IN_DIM + j] = (a0 + a1) + (a2 + a3);
  } else {
    float a0 = 0.f, a1 = 0.f;
#pragma unroll 4
    for (int m = 0; m < IN_DIM; m += 2) {
      a0 += W_out[k * IN_DIM + m] * b_v[m];
      a1 += W_out[k * IN_DIM + m + 1] * b_v[m + 1];
    }
    bc[k] = a0 + a1;
  }
}

// ---------------------------------------------------------------------------
// coord: clip -> *127 -> floor (matches reference exactly)
// ---------------------------------------------------------------------------
__device__ __forceinline__ void coordf(float c, int& i, float& fr) {
  float u = fminf(fmaxf(c, 0.f), 1.f) * 127.f;
  float uf = floorf(u);
  i = (int)uf;
  fr = u - uf;
}

// One quarter-task bilerp-accumulate: lane handles channels 4m..4m+3 of ITS
// sample; 4 float4 loads (= the 4 taps) + 16 FMA. All addresses per-lane.
__device__ __forceinline__ float4 bil4(float4 acc, const float* __restrict__ P,
                                       unsigned plBase, int iv, int iu,
                                       float fv, float fu, float wt, int m) {
  unsigned off = plBase + (unsigned)(iv * RES + iu) * CPL + 4u * m;
  unsigned du = (iu < 127) ? CPL : 0u;
  unsigned dv = (iv < 127) ? (unsigned)(RES * CPL) : 0u;
  float4 t0 = *(const float4*)(P + off);
  float4 t1 = *(const float4*)(P + off + du);
  float4 t2 = *(const float4*)(P + off + dv);
  float4 t3 = *(const float4*)(P + off + dv + du);
  float a = wt * (1.f - fu), bq = wt * fu;
  float w0 = a * (1.f - fv), w1 = bq * (1.f - fv), w2 = a * fv, w3 = bq * fv;
  acc.x += t0.x * w0 + t1.x * w1 + t2.x * w2 + t3.x * w3;
  acc.y += t0.y * w0 + t1.y * w1 + t2.y * w2 + t3.y * w3;
  acc.z += t0.z * w0 + t1.z * w1 + t2.z * w2 + t3.z * w3;
  acc.w += t0.w * w0 + t1.w * w1 + t2.w * w2 + t3.w * w3;
  return acc;
}

// ---------------------------------------------------------------------------
// Kernel 3: ONE WAVE PER POINT, quarter-task gathers. No __syncthreads (all
// LDS traffic is wave-local; hw waitcnt orders it). q=lane>>4, m=lane&15.
// ---------------------------------------------------------------------------
__global__ __launch_bounds__(256, 4) void fused_sample(
    const float* __restrict__ qpos, const float* __restrict__ planesT,
    const float* __restrict__ W_off, const float* __restrict__ b_off,
    const float* __restrict__ W_wt, const float* __restrict__ b_wt,
    float* __restrict__ waux, float* __restrict__ swtg,
    float* __restrict__ outp) {
  __shared__ float feat_lds[4][IN_DIM];
  __shared__ float offwt[4][32];  // 0..23 = off, 24..31 = wt
  int w = threadIdx.x >> 6, lane = threadIdx.x & 63;
  int q = lane >> 4, m = lane & 15;
  int p = blockIdx.x * 4 + w;
  int b = p >> 14;
  float qx = qpos[p * 3 + 0], qy = qpos[p * 3 + 1], qz = qpos[p * 3 + 2];
  unsigned bOff = (unsigned)b * 3u * PL_STRIDE;

  // ---- Phase A: feature. Quarter q = plane q (q==3 duplicates plane 2).
  {
    int ix, iy, iz;
    float fx, fy, fz;
    coordf(qx, ix, fx);
    coordf(qy, iy, fy);
    coordf(qz, iz, fz);
    // pl0 (xz): u=x,v=z ; pl1 (xy): u=x,v=y ; pl2 (yz): u=y,v=z
    unsigned off0 = bOff + 0u * PL_STRIDE + (unsigned)(iz * RES + ix) * CPL;
    unsigned off1 = bOff + 1u * PL_STRIDE + (unsigned)(iy * RES + ix) * CPL;
    unsigned off2 = bOff + 2u * PL_STRIDE + (unsigned)(iz * RES + iy) * CPL;
    unsigned du0 = (ix < 127) ? CPL : 0u, dv0 = (iz < 127) ? RES * CPL : 0u;
    unsigned du1 = (ix < 127) ? CPL : 0u, dv1 = (iy < 127) ? RES * CPL : 0u;
    unsigned du2 = (iy < 127) ? CPL : 0u, dv2 = (iz < 127) ? RES * CPL : 0u;
    unsigned offV = (q == 0) ? off0 : (q == 1) ? off1 : off2;
    unsigned duV = (q == 0) ? du0 : (q == 1) ? du1 : du2;
    unsigned dvV = (q == 0) ? dv0 : (q == 1) ? dv1 : dv2;
    float wxV = (q == 0) ? fx : (q == 1) ? fx : fy;
    float wyV = (q == 0) ? fz : (q == 1) ? fy : fz;
    offV += 4u * m;
    float4 t0 = *(const float4*)(planesT + offV);
    float4 t1 = *(const float4*)(planesT + offV + duV);
    float4 t2 = *(const float4*)(planesT + offV + dvV);
    float4 t3 = *(const float4*)(planesT + offV + dvV + duV);
    float cx = 1.f - wxV, cy = 1.f - wyV;
    float w0 = cx * cy, w1 = wxV * cy, w2 = cx * wyV, w3 = wxV * wyV;
    float4 f4;
    f4.x = t0.x * w0 + t1.x * w1 + t2.x * w2 + t3.x * w3;
    f4.y = t0.y * w0 + t1.y * w1 + t2.y * w2 + t3.y * w3;
    f4.z = t0.z * w0 + t1.z * w1 + t2.z * w2 + t3.z * w3;
    f4.w = t0.w * w0 + t1.w * w1 + t2.w * w2 + t3.w * w3;
    if (q < 3) {
      *(float4*)&feat_lds[w][q * 64 + 4 * m] = f4;
      *(float4*)(outp + (size_t)p * IN_DIM + q * 64 + 4 * m) = f4;  // residual
    }
  }

  // ---- Matvec: 32 outputs x 2-way k-split (wave-local LDS, no barrier).
  {
    int oj = lane & 31, kh = lane >> 5;
    const float* row = (oj < 24) ? (W_off + oj * IN_DIM)
                                 : (W_wt + (oj - 24) * IN_DIM);
    float bias = (oj < 24) ? b_off[oj] : b_wt[oj - 24];
    const float4* r4 = (const float4*)(row + kh * 96);
    const float4* fl = (const float4*)&feat_lds[w][kh * 96];
    float a0 = 0.f, a1 = 0.f, a2 = 0.f, a3 = 0.f;
#pragma unroll
    for (int k4 = 0; k4 < 24; ++k4) {
      float4 rv = r4[k4];
      float4 fv = fl[k4];
      a0 += rv.x * fv.x;
      a1 += rv.y * fv.y;
      a2 += rv.z * fv.z;
      a3 += rv.w * fv.w;
    }
    float acc = (a0 + a1) + (a2 + a3);
    acc += __shfl_xor(acc, 32);
    if (lane < 32) offwt[w][oj] = acc + bias;
  }

  // ---- Phase C: quarter q = sample 4*sb+q; 4 bilerps per load-quad.
  float4 acc0 = {0, 0, 0, 0}, acc1 = {0, 0, 0, 0}, acc2 = {0, 0, 0, 0};
  float swtA = 0.f;
#pragma unroll
  for (int sb = 0; sb < 2; ++sb) {
    int sl = 4 * sb + q;
    float ox = offwt[w][3 * sl + 0];
    float oy = offwt[w][3 * sl + 1];
    float oz = offwt[w][3 * sl + 2];
    float wt = offwt[w][24 + sl];
    swtA += wt;
    int ix, iy, iz;
    float fx, fy, fz;
    coordf(qx + ox, ix, fx);
    coordf(qy + oy, iy, fy);
    coordf(qz + oz, iz, fz);
    acc0 = bil4(acc0, planesT, bOff + 0u * PL_STRIDE, iz, ix, fz, fx, wt, m);
    acc1 = bil4(acc1, planesT, bOff + 1u * PL_STRIDE, iy, ix, fy, fx, wt, m);
    acc2 = bil4(acc2, planesT, bOff + 2u * PL_STRIDE, iz, iy, fz, fy, wt, m);
  }
  // sum the 4 quarters (lanes l, l^16, l^32, l^48 hold samples of same chans)
#define REDQ(v)                          \
  v.x += __shfl_xor(v.x, 16); v.y += __shfl_xor(v.y, 16); \
  v.z += __shfl_xor(v.z, 16); v.w += __shfl_xor(v.w, 16); \
  v.x += __shfl_xor(v.x, 32); v.y += __shfl_xor(v.y, 32); \
  v.z += __shfl_xor(v.z, 32); v.w += __shfl_xor(v.w, 32);
  REDQ(acc0)
  REDQ(acc1)
  REDQ(acc2)
#undef REDQ
  float4 wv = (q == 0) ? acc0 : (q == 1) ? acc1 : acc2;
  if (q < 3) *(float4*)(waux + (size_t)p * IN_DIM + q * 64 + 4 * m) = wv;
  swtA += __shfl_xor(swtA, 16);
  swtA += __shfl_xor(swtA, 32);
  if (lane == 0) swtg[p] = swtA;
}

// ---------------------------------------------------------------------------
// Kernel 4: out = waux @ Wc^T + swt*bc + b_out + feature (feature in out).
// lane = point (64/block); W via wave-uniform scalar loads; LDS = 192
// conflict-free ds_read_b32 per wave. FMA-floor bound (~31us).
// ---------------------------------------------------------------------------
__global__ __launch_bounds__(256) void out_gemm(
    const float* __restrict__ waux, const float* __restrict__ swtg,
    const float* __restrict__ WcT, const float* __restrict__ bc,
    const float* __restrict__ b_out, float* __restrict__ out) {
  __shared__ float at[64][193];  // pad 193: stride%32==1 -> 2-way (free)
  int tid = threadIdx.x;
  int w = tid >> 6, lane = tid & 63;
  int p0 = blockIdx.x * 64;

  const float4* src = (const float4*)(waux + (size_t)p0 * IN_DIM);
#pragma unroll
  for (int i = 0; i < 12; ++i) {
    int idx = tid + i * 256;
    int pp = idx / 48, k4 = idx % 48;
    float4 v = src[idx];
    at[pp][k4 * 4 + 0] = v.x;
    at[pp][k4 * 4 + 1] = v.y;
    at[pp][k4 * 4 + 2] = v.z;
    at[pp][k4 * 4 + 3] = v.w;
  }
  __syncthreads();

  int j0 = __builtin_amdgcn_readfirstlane(w * 48);  // wave-uniform j-block
  float acc[48] = {};
#pragma unroll 4
  for (int k = 0; k < 192; ++k) {
    float a = at[lane][k];
    const float* wr = WcT + k * IN_DIM + j0;  // uniform -> s_load
#pragma unroll
    for (int jj = 0; jj < 48; ++jj) acc[jj] += a * wr[jj];
  }

  int p = p0 + lane;
  float sw = swtg[p];
  size_t ob = (size_t)p * IN_DIM + j0;
#pragma unroll
  for (int g = 0; g < 12; ++g) {
    float4 o = *(const float4*)(out + ob + 4 * g);
    float4 r;
    r.x = acc[4 * g + 0] + sw * bc[j0 + 4 * g + 0] + b_out[j0 + 4 * g + 0] + o.x;
    r.y = acc[4 * g + 1] + sw * bc[j0 + 4 * g + 1] + b_out[j0 + 4 * g + 1] + o.y;
    r.z = acc[4 * g + 2] + sw * bc[j0 + 4 * g + 2] + b_out[j0 + 4 * g + 2] + o.z;
    r.w = acc[4 * g + 3] + sw * bc[j0 + 4 * g + 3] + b_out[j0 + 4 * g + 3] + o.w;
    *(float4*)(out + ob + 4 * g) = r;
  }
}

// ---------------------------------------------------------------------------
extern "C" void kernel_launch(void* const* d_in, const int* in_sizes, int n_in,
                              void* d_out, int out_size, void* d_ws,
                              size_t ws_size, hipStream_t stream) {
  const float* qpos  = (const float*)d_in[0];
  const float* xz    = (const float*)d_in[1];
  const float* xy    = (const float*)d_in[2];
  const float* yz    = (const float*)d_in[3];
  const float* W_v   = (const float*)d_in[4];
  const float* b_v   = (const float*)d_in[5];
  const float* W_out = (const float*)d_in[6];
  const float* b_out = (const float*)d_in[7];
  const float* W_off = (const float*)d_in[8];
  const float* b_off = (const float*)d_in[9];
  const float* W_wt  = (const float*)d_in[10];
  const float* b_wt  = (const float*)d_in[11];

  float* ws      = (float*)d_ws;
  float* planesT = ws;
  float* waux    = planesT + PLANES_T_FLOATS;
  float* swtg    = waux + (size_t)NPTS * IN_DIM;
  float* WcT     = swtg + NPTS;
  float* bc      = WcT + IN_DIM * IN_DIM;
  float* out     = (float*)d_out;

  hipLaunchKernelGGL(transpose_planes, dim3(BS * 3 * RES * 2), dim3(256), 0,
                     stream, xz, xy, yz, planesT);
  hipLaunchKernelGGL(precompute_wc, dim3(IN_DIM + 1), dim3(IN_DIM), 0, stream,
                     W_v, b_v, W_out, WcT, bc);
  hipLaunchKernelGGL(fused_sample, dim3(NPTS / 4), dim3(256), 0, stream, qpos,
                     planesT, W_off, b_off, W_wt, b_wt, waux, swtg, out);
  hipLaunchKernelGGL(out_gemm, dim3(NPTS / 64), dim3(256), 0, stream, waux,
                     swtg, WcT, bc, b_out, out);
}

// Round 8
// 479.179 us; speedup vs baseline: 1.0021x; 1.0021x over previous
//
#include <hip/hip_runtime.h>

#define BS 4
#define NS 16384
#define S_SAMP 8
#define CPL 64
#define RES 128
#define IN_DIM 192
#define NPTS (BS * NS)                 // 65536
#define PL_STRIDE (RES * RES * CPL)    // 1048576 floats per (batch,plane)
#define PLANES_T_FLOATS (BS * 3 * PL_STRIDE)

// ---------------------------------------------------------------------------
// Kernel 1: transpose planes [B,C,H,W] -> [B,pl,H,W,C].
// ---------------------------------------------------------------------------
__global__ __launch_bounds__(256) void transpose_planes(
    const float* __restrict__ xz, const float* __restrict__ xy,
    const float* __restrict__ yz, float* __restrict__ T) {
  __shared__ float tile[64][65];
  int blk = blockIdx.x;
  int xh = blk & 1;
  int y  = (blk >> 1) & 127;
  int pl = (blk >> 8) % 3;
  int b  = blk / 768;
  const float* s = ((pl == 0) ? xz : (pl == 1) ? xy : yz) +
                   (size_t)b * CPL * RES * RES + y * RES + xh * 64;
  int tid = threadIdx.x;
  int xi = tid & 15, c0 = tid >> 4;
#pragma unroll
  for (int r = 0; r < 4; ++r) {
    int c = c0 + r * 16;
    float4 v = *(const float4*)(s + (size_t)c * RES * RES + 4 * xi);
    tile[c][4 * xi + 0] = v.x;
    tile[c][4 * xi + 1] = v.y;
    tile[c][4 * xi + 2] = v.z;
    tile[c][4 * xi + 3] = v.w;
  }
  __syncthreads();
  float* d = T + ((size_t)(b * 3 + pl) * RES * RES + (size_t)y * RES + xh * 64) * CPL;
  int cj = tid & 15, x0 = tid >> 4;
#pragma unroll
  for (int r = 0; r < 4; ++r) {
    int x = x0 + r * 16;
    float4 v;
    v.x = tile[4 * cj + 0][x];
    v.y = tile[4 * cj + 1][x];
    v.z = tile[4 * cj + 2][x];
    v.w = tile[4 * cj + 3][x];
    *(float4*)(d + (size_t)x * CPL + 4 * cj) = v;
  }
}

// ---------------------------------------------------------------------------
// Kernel 2: Wc = W_out @ W_v (WcT[k][j]), bc = W_out @ b_v.
// ---------------------------------------------------------------------------
__global__ __launch_bounds__(192) void precompute_wc(
    const float* __restrict__ W_v, const float* __restrict__ b_v,
    const float* __restrict__ W_out, float* __restrict__ WcT,
    float* __restrict__ bc) {
  int j = blockIdx.x;
  int k = threadIdx.x;
  if (j < IN_DIM) {
    float a0 = 0.f, a1 = 0.f, a2 = 0.f, a3 = 0.f;
#pragma unroll 4
    for (int m = 0; m < IN_DIM; m += 4) {
      a0 += W_out[j * IN_DIM + m + 0] * W_v[(m + 0) * IN_DIM + k];
      a1 += W_out[j * IN_DIM + m + 1] * W_v[(m + 1) * IN_DIM + k];
      a2 += W_out[j * IN_DIM + m + 2] * W_v[(m + 2) * IN_DIM + k];
      a3 += W_out[j * IN_DIM + m + 3] * W_v[(m + 3) * IN_DIM + k];
    }
    WcT[k * IN_DIM + j] = (a0 + a1) + (a2 + a3);
  } else {
    float a0 = 0.f, a1 = 0.f;
#pragma unroll 4
    for (int m = 0; m < IN_DIM; m += 2) {
      a0 += W_out[k * IN_DIM + m] * b_v[m];
      a1 += W_out[k * IN_DIM + m + 1] * b_v[m + 1];
    }
    bc[k] = a0 + a1;
  }
}

// clip -> *127 -> floor (matches reference exactly)
__device__ __forceinline__ void coordf(float c, int& i, float& fr) {
  float u = fminf(fmaxf(c, 0.f), 1.f) * 127.f;
  float uf = floorf(u);
  i = (int)uf;
  fr = u - uf;
}

// ---------------------------------------------------------------------------
// Kernel 3: feature (12 taps) + off/wt matvec. Stores: feature -> out
// (residual), sample ABS positions + wt -> offpt[p][32] (s*4 + {x,y,z,wt}),
// swt -> swtg. One wave per point; q=lane>>4 handles plane q (q==3 idle).
// ---------------------------------------------------------------------------
__global__ __launch_bounds__(256, 4) void feat_off(
    const float* __restrict__ qpos, const float* __restrict__ planesT,
    const float* __restrict__ W_off, const float* __restrict__ b_off,
    const float* __restrict__ W_wt, const float* __restrict__ b_wt,
    float* __restrict__ offpt, float* __restrict__ swtg,
    float* __restrict__ outp) {
  __shared__ float feat_lds[4][IN_DIM];
  __shared__ float offwt[4][32];  // 0..23 = off, 24..31 = wt
  int w = threadIdx.x >> 6, lane = threadIdx.x & 63;
  int q = lane >> 4, m = lane & 15;
  int p = blockIdx.x * 4 + w;
  int b = p >> 14;
  float qx = qpos[p * 3 + 0], qy = qpos[p * 3 + 1], qz = qpos[p * 3 + 2];
  unsigned bOff = (unsigned)b * 3u * PL_STRIDE;

  {  // feature bilerp, quarter q = plane q
    int ix, iy, iz;
    float fx, fy, fz;
    coordf(qx, ix, fx);
    coordf(qy, iy, fy);
    coordf(qz, iz, fz);
    unsigned off0 = bOff + 0u * PL_STRIDE + (unsigned)(iz * RES + ix) * CPL;
    unsigned off1 = bOff + 1u * PL_STRIDE + (unsigned)(iy * RES + ix) * CPL;
    unsigned off2 = bOff + 2u * PL_STRIDE + (unsigned)(iz * RES + iy) * CPL;
    unsigned du0 = (ix < 127) ? CPL : 0u, dv0 = (iz < 127) ? RES * CPL : 0u;
    unsigned du1 = (ix < 127) ? CPL : 0u, dv1 = (iy < 127) ? RES * CPL : 0u;
    unsigned du2 = (iy < 127) ? CPL : 0u, dv2 = (iz < 127) ? RES * CPL : 0u;
    unsigned offV = (q == 0) ? off0 : (q == 1) ? off1 : off2;
    unsigned duV = (q == 0) ? du0 : (q == 1) ? du1 : du2;
    unsigned dvV = (q == 0) ? dv0 : (q == 1) ? dv1 : dv2;
    float wxV = (q == 0) ? fx : (q == 1) ? fx : fy;
    float wyV = (q == 0) ? fz : (q == 1) ? fy : fz;
    offV += 4u * m;
    float4 t0 = *(const float4*)(planesT + offV);
    float4 t1 = *(const float4*)(planesT + offV + duV);
    float4 t2 = *(const float4*)(planesT + offV + dvV);
    float4 t3 = *(const float4*)(planesT + offV + dvV + duV);
    float cx = 1.f - wxV, cy = 1.f - wyV;
    float w0 = cx * cy, w1 = wxV * cy, w2 = cx * wyV, w3 = wxV * wyV;
    float4 f4;
    f4.x = t0.x * w0 + t1.x * w1 + t2.x * w2 + t3.x * w3;
    f4.y = t0.y * w0 + t1.y * w1 + t2.y * w2 + t3.y * w3;
    f4.z = t0.z * w0 + t1.z * w1 + t2.z * w2 + t3.z * w3;
    f4.w = t0.w * w0 + t1.w * w1 + t2.w * w2 + t3.w * w3;
    if (q < 3) {
      *(float4*)&feat_lds[w][q * 64 + 4 * m] = f4;
      *(float4*)(outp + (size_t)p * IN_DIM + q * 64 + 4 * m) = f4;  // residual
    }
  }

  {  // matvec: 32 outputs x 2-way k-split (wave-local, no barrier)
    int oj = lane & 31, kh = lane >> 5;
    const float* row = (oj < 24) ? (W_off + oj * IN_DIM)
                                 : (W_wt + (oj - 24) * IN_DIM);
    float bias = (oj < 24) ? b_off[oj] : b_wt[oj - 24];
    const float4* r4 = (const float4*)(row + kh * 96);
    const float4* fl = (const float4*)&feat_lds[w][kh * 96];
    float a0 = 0.f, a1 = 0.f, a2 = 0.f, a3 = 0.f;
#pragma unroll
    for (int k4 = 0; k4 < 24; ++k4) {
      float4 rv = r4[k4];
      float4 fv = fl[k4];
      a0 += rv.x * fv.x;
      a1 += rv.y * fv.y;
      a2 += rv.z * fv.z;
      a3 += rv.w * fv.w;
    }
    float acc = (a0 + a1) + (a2 + a3);
    acc += __shfl_xor(acc, 32);
    if (lane < 32) offwt[w][oj] = acc + bias;
  }

  // emit absolute sample positions + wt: offpt[p*32 + s*4 + e]
  if (lane < 32) {
    int s = lane >> 2, e = lane & 3;
    float val;
    if (e == 3) {
      val = offwt[w][24 + s];
    } else {
      float qc = (e == 0) ? qx : (e == 1) ? qy : qz;
      val = qc + offwt[w][3 * s + e];
    }
    offpt[(size_t)p * 32 + lane] = val;
  }
  if (lane == 0) {
    float sw = 0.f;
#pragma unroll
    for (int s = 0; s < S_SAMP; ++s) sw += offwt[w][24 + s];
    swtg[p] = sw;
  }
}

// ---------------------------------------------------------------------------
// Kernel 4 (x3): plane-sharded gather pass. blockIdx -> XCD via the mod-8
// round-robin heuristic; batch b pinned to XCDs {2b,2b+1} so each XCD's
// gather working set = ONE (batch,plane) slab = 4MB = its L2. Quarter-task:
// q=lane>>4 handles samples {q,q+4}; m=lane&15 handles channels 4m..4m+3.
// Writes waux[p][PL*64 .. PL*64+63] (disjoint across passes).
// ---------------------------------------------------------------------------
template <int PL>
__global__ __launch_bounds__(256, 8) void gather_pass(
    const float* __restrict__ offpt, const float* __restrict__ planesT,
    float* __restrict__ waux) {
  int w = threadIdx.x >> 6, lane = threadIdx.x & 63;
  int q = lane >> 4, m = lane & 15;
  int i = blockIdx.x;
  int xcd = i & 7, j = i >> 3;
  int b = xcd >> 1;
  int pblk = (xcd & 1) * 2048 + j;          // within-batch block 0..4095
  int p = b * NS + pblk * 4 + w;
  const float* P = planesT + ((size_t)b * 3 + PL) * PL_STRIDE;
  const float4* sp = (const float4*)(offpt + (size_t)p * 32);

  float4 acc = {0.f, 0.f, 0.f, 0.f};
#pragma unroll
  for (int sb = 0; sb < 2; ++sb) {
    float4 s4 = sp[q + sb * 4];  // (px,py,pz,wt)
    float u = (PL == 0) ? s4.x : (PL == 1) ? s4.x : s4.y;
    float v = (PL == 0) ? s4.z : (PL == 1) ? s4.y : s4.z;
    int iu, iv;
    float fu, fv;
    coordf(u, iu, fu);
    coordf(v, iv, fv);
    unsigned off = (unsigned)(iv * RES + iu) * CPL + 4u * m;
    unsigned du = (iu < 127) ? CPL : 0u;
    unsigned dv = (iv < 127) ? (unsigned)(RES * CPL) : 0u;
    float4 t0 = *(const float4*)(P + off);
    float4 t1 = *(const float4*)(P + off + du);
    float4 t2 = *(const float4*)(P + off + dv);
    float4 t3 = *(const float4*)(P + off + dv + du);
    float wt = s4.w;
    float a = wt * (1.f - fu), bq = wt * fu;
    float w0 = a * (1.f - fv), w1 = bq * (1.f - fv), w2 = a * fv, w3 = bq * fv;
    acc.x += t0.x * w0 + t1.x * w1 + t2.x * w2 + t3.x * w3;
    acc.y += t0.y * w0 + t1.y * w1 + t2.y * w2 + t3.y * w3;
    acc.z += t0.z * w0 + t1.z * w1 + t2.z * w2 + t3.z * w3;
    acc.w += t0.w * w0 + t1.w * w1 + t2.w * w2 + t3.w * w3;
  }
  // reduce over q (samples): lanes l, l^16, l^32 hold same channel group
  acc.x += __shfl_xor(acc.x, 16); acc.y += __shfl_xor(acc.y, 16);
  acc.z += __shfl_xor(acc.z, 16); acc.w += __shfl_xor(acc.w, 16);
  acc.x += __shfl_xor(acc.x, 32); acc.y += __shfl_xor(acc.y, 32);
  acc.z += __shfl_xor(acc.z, 32); acc.w += __shfl_xor(acc.w, 32);
  if (q == 0)
    *(float4*)(waux + (size_t)p * IN_DIM + PL * 64 + 4 * m) = acc;
}

// ---------------------------------------------------------------------------
// Kernel 5: out = waux @ Wc^T + swt*bc + b_out + feature (feature in out).
// 32-pt tile, flat k-loop, batched ds_reads, vector WcT loads.
// ---------------------------------------------------------------------------
__global__ __launch_bounds__(256) void out_gemm(
    const float* __restrict__ waux, const float* __restrict__ swtg,
    const float* __restrict__ WcT, const float* __restrict__ bc,
    const float* __restrict__ b_out, float* __restrict__ out) {
  __shared__ float at[32 * IN_DIM];  // 24KB waux tile
  int tid = threadIdx.x;
  int w = tid >> 6, lane = tid & 63;
  int p0 = blockIdx.x * 32;

  const float4* src = (const float4*)(waux + (size_t)p0 * IN_DIM);
  float4* dst4 = (float4*)at;
#pragma unroll
  for (int i = 0; i < 6; ++i) dst4[tid + i * 256] = src[tid + i * 256];
  __syncthreads();

  int pw = w * 8;
  float acc[8][3] = {};
#pragma unroll 2
  for (int k4 = 0; k4 < 48; ++k4) {
    float v0[4], v1[4], v2[4];
#pragma unroll
    for (int kk = 0; kk < 4; ++kk) {
      const float* r = WcT + (k4 * 4 + kk) * IN_DIM;
      v0[kk] = r[lane];
      v1[kk] = r[64 + lane];
      v2[kk] = r[128 + lane];
    }
    float4 a[8];
#pragma unroll
    for (int qq = 0; qq < 8; ++qq)
      a[qq] = *(const float4*)&at[(pw + qq) * IN_DIM + k4 * 4];
#pragma unroll
    for (int qq = 0; qq < 8; ++qq) {
      acc[qq][0] += v0[0] * a[qq].x + v0[1] * a[qq].y + v0[2] * a[qq].z + v0[3] * a[qq].w;
      acc[qq][1] += v1[0] * a[qq].x + v1[1] * a[qq].y + v1[2] * a[qq].z + v1[3] * a[qq].w;
      acc[qq][2] += v2[0] * a[qq].x + v2[1] * a[qq].y + v2[2] * a[qq].z + v2[3] * a[qq].w;
    }
  }

  float bcv[3], bov[3];
#pragma unroll
  for (int t = 0; t < 3; ++t) {
    bcv[t] = bc[lane + t * 64];
    bov[t] = b_out[lane + t * 64];
  }
#pragma unroll
  for (int qq = 0; qq < 8; ++qq) {
    int p = p0 + pw + qq;
    float sw = swtg[p];
#pragma unroll
    for (int t = 0; t < 3; ++t) {
      size_t o = (size_t)p * IN_DIM + lane + t * 64;
      out[o] = acc[qq][t] + sw * bcv[t] + bov[t] + out[o];
    }
  }
}

// ---------------------------------------------------------------------------
extern "C" void kernel_launch(void* const* d_in, const int* in_sizes, int n_in,
                              void* d_out, int out_size, void* d_ws,
                              size_t ws_size, hipStream_t stream) {
  const float* qpos  = (const float*)d_in[0];
  const float* xz    = (const float*)d_in[1];
  const float* xy    = (const float*)d_in[2];
  const float* yz    = (const float*)d_in[3];
  const float* W_v   = (const float*)d_in[4];
  const float* b_v   = (const float*)d_in[5];
  const float* W_out = (const float*)d_in[6];
  const float* b_out = (const float*)d_in[7];
  const float* W_off = (const float*)d_in[8];
  const float* b_off = (const float*)d_in[9];
  const float* W_wt  = (const float*)d_in[10];
  const float* b_wt  = (const float*)d_in[11];

  float* ws      = (float*)d_ws;
  float* planesT = ws;                                   // 50.3 MB
  float* waux    = planesT + PLANES_T_FLOATS;            // 50.3 MB
  float* offpt   = waux + (size_t)NPTS * IN_DIM;         // 8.4 MB
  float* swtg    = offpt + (size_t)NPTS * 32;            // 256 KB
  float* WcT     = swtg + NPTS;                          // 144 KB
  float* bc      = WcT + IN_DIM * IN_DIM;                // 768 B
  float* out     = (float*)d_out;
  // total ws need: ~109.4 MB

  hipLaunchKernelGGL(transpose_planes, dim3(BS * 3 * RES * 2), dim3(256), 0,
                     stream, xz, xy, yz, planesT);
  hipLaunchKernelGGL(precompute_wc, dim3(IN_DIM + 1), dim3(IN_DIM), 0, stream,
                     W_v, b_v, W_out, WcT, bc);
  hipLaunchKernelGGL(feat_off, dim3(NPTS / 4), dim3(256), 0, stream, qpos,
                     planesT, W_off, b_off, W_wt, b_wt, offpt, swtg, out);
  hipLaunchKernelGGL(gather_pass<0>, dim3(NPTS / 4), dim3(256), 0, stream,
                     offpt, planesT, waux);
  hipLaunchKernelGGL(gather_pass<1>, dim3(NPTS / 4), dim3(256), 0, stream,
                     offpt, planesT, waux);
  hipLaunchKernelGGL(gather_pass<2>, dim3(NPTS / 4), dim3(256), 0, stream,
                     offpt, planesT, waux);
  hipLaunchKernelGGL(out_gemm, dim3(NPTS / 32), dim3(256), 0, stream, waux,
                     swtg, WcT, bc, b_out, out);
}